// Round 2
// baseline (443.838 us; speedup 1.0000x reference)
//
#include <hip/hip_runtime.h>
#include <stdint.h>

// Problem constants
#define B_ 16
#define T_ 512
#define F_ 32
#define CI_ 128
#define CO_ 128
#define K_ 3
#define LPAD 4              // DIL*(K-1)
#define TM 64               // output rows per tile
#define NT 4                // tiles per block (t-split: each block does T/2 = 256 rows)
#define THALF 256           // T_/2
#define XROWS (TM + LPAD)   // 68 staged x rows
#define XPITCH 136          // bf16/row: 128 data + 8 pad (272B; row bank-step 4)
#define WPITCH 32
#define CHUNK_ELEMS (CO_ * WPITCH) // 4096 elems per (tap,kstep) chunk
#define NCHUNK 12           // 3 taps * 4 ksteps of K=32
#define NXV 5               // ceil(68*32 / 512) float4 per thread

typedef __attribute__((ext_vector_type(8))) __bf16 bf16x8;
typedef __attribute__((ext_vector_type(4))) float f32x4;

__device__ __forceinline__ uint16_t f2bf(float x) {
  uint32_t u = __builtin_bit_cast(uint32_t, x);
  u += 0x7fffu + ((u >> 16) & 1u);
  return (uint16_t)(u >> 16);
}

// Coalesced repack: w[f][o][i][k] fp32 -> wt2[f][tap*4+kstep][o][32] bf16.
__global__ __launch_bounds__(256) void repack_w(const float* __restrict__ w,
                                                uint16_t* __restrict__ wt2) {
  int idx = blockIdx.x * 256 + threadIdx.x; // (f*CO+o)*CI + i
  int i = idx & (CI_ - 1);
  int fo = idx >> 7;
  int o = fo & (CO_ - 1);
  int f = fo >> 7;
  const float* src = w + (size_t)idx * K_;
  float a0 = src[0], a1 = src[1], a2 = src[2];
  size_t base = ((size_t)f * NCHUNK + (i >> 5)) * CHUNK_ELEMS + o * WPITCH + (i & 31);
  wt2[base] = f2bf(a0);
  wt2[base + 4 * (size_t)CHUNK_ELEMS] = f2bf(a1);
  wt2[base + 8 * (size_t)CHUNK_ELEMS] = f2bf(a2);
}

// Block = (f, b, th), 1024 blocks -> 4 resident/CU (LDS 4x37.4KB = 149.5KB,
// VGPR<=64 via __launch_bounds__(512,8) -> 32 waves/CU, 100% occupancy target).
// 512 threads = 8 waves, each wave owns 16 output cols (co) with its W
// fragments pinned in 48 VGPRs as the MFMA *A* operand.
// D = W(A) * x(B): D row = o (quad*4+reg -> 4 consecutive co per lane),
// D col = t (l15). Epilogue is 4 float4 stores per wave per tile.
// xs double-buffered -> ONE barrier per tile; x prefetched 2 tiles ahead.
template <bool PACKED>
__global__ __launch_bounds__(512, 8) void conv_main(
    const float* __restrict__ x, const uint16_t* __restrict__ wt2,
    const float* __restrict__ wraw, const float* __restrict__ bias,
    float* __restrict__ y) {
  __shared__ __align__(16) uint16_t xs[2][XROWS * XPITCH]; // 36,992 B

  const int bid = blockIdx.x;
  const int f = bid >> 5;          // 0..31 (same-f blocks contiguous for L2 W reuse)
  const int b = (bid >> 1) & 15;   // 0..15
  const int th = bid & 1;          // 0..1 -> t half
  const int t00 = th * THALF;

  const int tid = threadIdx.x;
  const int lane = tid & 63;
  const int wave = tid >> 6;   // 0..7 -> col group
  const int l15 = lane & 15;
  const int quad = lane >> 4;
  const int co0 = wave * 16;

  // ---- W fragments -> registers (once per block) ----
  // A-operand layout: lane row = l15 (o = co0+l15), k-chunk = quad*8..quad*8+7.
  bf16x8 wreg[NCHUNK];
  if constexpr (PACKED) {
    const uint16_t* wp = wt2 + (size_t)f * NCHUNK * CHUNK_ELEMS + (co0 + l15) * WPITCH + quad * 8;
#pragma unroll
    for (int c = 0; c < NCHUNK; ++c)
      wreg[c] = *(const bf16x8*)(wp + c * CHUNK_ELEMS);
  } else {
#pragma unroll
    for (int c = 0; c < NCHUNK; ++c) {
      int tap = c >> 2, i0 = (c & 3) * 32 + quad * 8;
      const float* ws = wraw + (((size_t)(f * CO_ + co0 + l15)) * CI_ + i0) * K_ + tap;
      union { bf16x8 v; uint16_t h[8]; } u;
#pragma unroll
      for (int j = 0; j < 8; ++j) u.h[j] = f2bf(ws[j * K_]);
      wreg[c] = u.v;
    }
  }
  // Bias along o: lane covers o = co0 + quad*4 + r, r=0..3.
  const float4 bb = *(const float4*)(bias + f * CO_ + co0 + quad * 4);

  const float* xb = x + ((size_t)b * T_ * F_ + f) * CI_;
  float4 xr[NXV];

  auto load_x = [&](int t0) { // issue global loads for tile window into regs
#pragma unroll
    for (int it = 0; it < NXV; ++it) {
      int idx = tid + it * 512;
      if (idx < XROWS * 32) {
        int row = idx >> 5, c4 = idx & 31;
        int t = t0 - LPAD + row;
        xr[it] = (t >= 0) ? *(const float4*)(xb + (size_t)t * (F_ * CI_) + c4 * 4)
                          : make_float4(0.f, 0.f, 0.f, 0.f);
      }
    }
  };
  auto store_x = [&](uint16_t* dst) { // cvt + write staged regs into LDS buffer
#pragma unroll
    for (int it = 0; it < NXV; ++it) {
      int idx = tid + it * 512;
      if (idx < XROWS * 32) {
        int row = idx >> 5, c4 = idx & 31;
        uint2 pk;
        pk.x = (uint32_t)f2bf(xr[it].x) | ((uint32_t)f2bf(xr[it].y) << 16);
        pk.y = (uint32_t)f2bf(xr[it].z) | ((uint32_t)f2bf(xr[it].w) << 16);
        *(uint2*)&dst[row * XPITCH + c4 * 4] = pk;
      }
    }
  };

  load_x(t00);
  store_x(xs[0]);
  load_x(t00 + TM); // prefetch tile 1
  __syncthreads();

  const int abase = l15 * XPITCH + quad * 8; // elem offset; rest is static imms

#pragma unroll 1
  for (int j = 0; j < NT; ++j) {
    const int t0 = t00 + j * TM;
    const uint16_t* xbuf = xs[j & 1];

    f32x4 acc[4];
#pragma unroll
    for (int fm = 0; fm < 4; ++fm) acc[fm] = (f32x4){bb.x, bb.y, bb.z, bb.w};

#pragma unroll
    for (int c = 0; c < NCHUNK; ++c) {
      const int tap = c >> 2, ks = c & 3;
#pragma unroll
      for (int fm = 0; fm < 4; ++fm) {
        // x fragment (B operand): col = l15 -> t' within 16-row group fm.
        bf16x8 av = *(const bf16x8*)&xbuf[abase + (2 * tap + fm * 16) * XPITCH + ks * 32];
        acc[fm] = __builtin_amdgcn_mfma_f32_16x16x32_bf16(wreg[c], av, acc[fm], 0, 0, 0);
      }
    }

    // Epilogue: D row = o' = quad*4 + r (consecutive co), col = t' = l15.
    // Lane stores float4 at y[b, t0 + fm*16 + l15, f, co0 + quad*4].
    float* yb = y + (((size_t)b * T_ + t0 + l15) * F_ + f) * CO_ + co0 + quad * 4;
#pragma unroll
    for (int fm = 0; fm < 4; ++fm) {
      *(float4*)(yb + (size_t)(fm * 16) * (F_ * CO_)) =
          make_float4(acc[fm][0], acc[fm][1], acc[fm][2], acc[fm][3]);
    }

    if (j < NT - 1) {
      store_x(xs[(j + 1) & 1]);             // write NEXT tile into idle buffer
      if (j < NT - 2) load_x(t0 + 2 * TM);  // refill prefetch regs
      __syncthreads();                      // xs[(j+1)&1] ready for everyone
    }
  }
}

extern "C" void kernel_launch(void* const* d_in, const int* in_sizes, int n_in,
                              void* d_out, int out_size, void* d_ws, size_t ws_size,
                              hipStream_t stream) {
  const float* x = (const float*)d_in[0];
  const float* w = (const float*)d_in[1];
  const float* bias = (const float*)d_in[2];
  float* y = (float*)d_out;

  const size_t wt2_bytes = (size_t)F_ * NCHUNK * CHUNK_ELEMS * sizeof(uint16_t); // 3.0 MiB
  const int main_blocks = F_ * B_ * 2; // 1024 blocks = 4 resident/CU

  if (ws_size >= wt2_bytes) {
    uint16_t* wt2 = (uint16_t*)d_ws;
    const int total = F_ * CO_ * CI_; // 524288
    repack_w<<<total / 256, 256, 0, stream>>>(w, wt2);
    conv_main<true><<<main_blocks, 512, 0, stream>>>(x, wt2, w, bias, y);
  } else {
    conv_main<false><<<main_blocks, 512, 0, stream>>>(x, (const uint16_t*)nullptr, w, bias, y);
  }
}

// Round 3
// 293.896 us; speedup vs baseline: 1.5102x; 1.5102x over previous
//
#include <hip/hip_runtime.h>
#include <stdint.h>

// Problem constants
#define B_ 16
#define T_ 512
#define F_ 32
#define CI_ 128
#define CO_ 128
#define K_ 3
#define LPAD 4              // DIL*(K-1)
#define TM 64               // output rows per tile
#define NT 4                // tiles per block (t-split: each block does T/2 = 256 rows)
#define THALF 256           // T_/2
#define XROWS (TM + LPAD)   // 68 staged x rows
#define XPITCH 136          // bf16/row: 128 data + 8 pad (272B; row bank-step 4)
#define WPITCH 32
#define CHUNK_ELEMS (CO_ * WPITCH) // 4096 elems per (tap,kstep) chunk
#define NCHUNK 12           // 3 taps * 4 ksteps of K=32
#define NXV 5               // ceil(68*32 / 512) float4 per thread

typedef __attribute__((ext_vector_type(8))) __bf16 bf16x8;
typedef __attribute__((ext_vector_type(4))) float f32x4;

__device__ __forceinline__ uint16_t f2bf(float x) {
  uint32_t u = __builtin_bit_cast(uint32_t, x);
  u += 0x7fffu + ((u >> 16) & 1u);
  return (uint16_t)(u >> 16);
}

// Coalesced repack: w[f][o][i][k] fp32 -> wt2[f][tap*4+kstep][o][32] bf16.
__global__ __launch_bounds__(256) void repack_w(const float* __restrict__ w,
                                                uint16_t* __restrict__ wt2) {
  int idx = blockIdx.x * 256 + threadIdx.x; // (f*CO+o)*CI + i
  int i = idx & (CI_ - 1);
  int fo = idx >> 7;
  int o = fo & (CO_ - 1);
  int f = fo >> 7;
  const float* src = w + (size_t)idx * K_;
  float a0 = src[0], a1 = src[1], a2 = src[2];
  size_t base = ((size_t)f * NCHUNK + (i >> 5)) * CHUNK_ELEMS + o * WPITCH + (i & 31);
  wt2[base] = f2bf(a0);
  wt2[base + 4 * (size_t)CHUNK_ELEMS] = f2bf(a1);
  wt2[base + 8 * (size_t)CHUNK_ELEMS] = f2bf(a2);
}

// Block = (f, b, th), 1024 blocks. Residency is LDS-limited: 37,376 B x 4 =
// 149.5 KB <= 160 KB -> 4 blocks/CU = 32 waves/CU, REQUIRING VGPR <= 64.
// __launch_bounds__(512, 4) reproduces R1's exact 64-VGPR allocation (the
// (512,8) variant clamped to 32 VGPRs and spilled ~600 MB to scratch - R2).
// 512 threads = 8 waves, each wave owns 16 output cols (co) with its W
// fragments pinned in 48 VGPRs as the MFMA *A* operand.
// D = W(A) * x(B): D row = o (quad*4+reg -> 4 consecutive co per lane),
// D col = t (l15). Epilogue is 4 float4 stores per wave per tile.
// xs double-buffered -> ONE barrier per tile; x prefetched 2 tiles ahead.
template <bool PACKED>
__global__ __launch_bounds__(512, 4) void conv_main(
    const float* __restrict__ x, const uint16_t* __restrict__ wt2,
    const float* __restrict__ wraw, const float* __restrict__ bias,
    float* __restrict__ y) {
  __shared__ __align__(16) uint16_t xs[2][XROWS * XPITCH]; // 36,992 B

  const int bid = blockIdx.x;
  const int f = bid >> 5;          // 0..31 (same-f blocks contiguous for L2 W reuse)
  const int b = (bid >> 1) & 15;   // 0..15
  const int th = bid & 1;          // 0..1 -> t half
  const int t00 = th * THALF;

  const int tid = threadIdx.x;
  const int lane = tid & 63;
  const int wave = tid >> 6;   // 0..7 -> col group
  const int l15 = lane & 15;
  const int quad = lane >> 4;
  const int co0 = wave * 16;

  // ---- W fragments -> registers (once per block) ----
  // A-operand layout: lane row = l15 (o = co0+l15), k-chunk = quad*8..quad*8+7.
  bf16x8 wreg[NCHUNK];
  if constexpr (PACKED) {
    const uint16_t* wp = wt2 + (size_t)f * NCHUNK * CHUNK_ELEMS + (co0 + l15) * WPITCH + quad * 8;
#pragma unroll
    for (int c = 0; c < NCHUNK; ++c)
      wreg[c] = *(const bf16x8*)(wp + c * CHUNK_ELEMS);
  } else {
#pragma unroll
    for (int c = 0; c < NCHUNK; ++c) {
      int tap = c >> 2, i0 = (c & 3) * 32 + quad * 8;
      const float* ws = wraw + (((size_t)(f * CO_ + co0 + l15)) * CI_ + i0) * K_ + tap;
      union { bf16x8 v; uint16_t h[8]; } u;
#pragma unroll
      for (int j = 0; j < 8; ++j) u.h[j] = f2bf(ws[j * K_]);
      wreg[c] = u.v;
    }
  }
  // Bias along o: lane covers o = co0 + quad*4 + r, r=0..3.
  const float4 bb = *(const float4*)(bias + f * CO_ + co0 + quad * 4);

  const float* xb = x + ((size_t)b * T_ * F_ + f) * CI_;
  float4 xr[NXV];

  auto load_x = [&](int t0) { // issue global loads for tile window into regs
#pragma unroll
    for (int it = 0; it < NXV; ++it) {
      int idx = tid + it * 512;
      if (idx < XROWS * 32) {
        int row = idx >> 5, c4 = idx & 31;
        int t = t0 - LPAD + row;
        xr[it] = (t >= 0) ? *(const float4*)(xb + (size_t)t * (F_ * CI_) + c4 * 4)
                          : make_float4(0.f, 0.f, 0.f, 0.f);
      }
    }
  };
  auto store_x = [&](uint16_t* dst) { // cvt + write staged regs into LDS buffer
#pragma unroll
    for (int it = 0; it < NXV; ++it) {
      int idx = tid + it * 512;
      if (idx < XROWS * 32) {
        int row = idx >> 5, c4 = idx & 31;
        uint2 pk;
        pk.x = (uint32_t)f2bf(xr[it].x) | ((uint32_t)f2bf(xr[it].y) << 16);
        pk.y = (uint32_t)f2bf(xr[it].z) | ((uint32_t)f2bf(xr[it].w) << 16);
        *(uint2*)&dst[row * XPITCH + c4 * 4] = pk;
      }
    }
  };

  load_x(t00);
  store_x(xs[0]);
  load_x(t00 + TM); // prefetch tile 1
  __syncthreads();

  const int abase = l15 * XPITCH + quad * 8; // elem offset; rest is static imms

#pragma unroll 1
  for (int j = 0; j < NT; ++j) {
    const int t0 = t00 + j * TM;
    const uint16_t* xbuf = xs[j & 1];

    f32x4 acc[4];
#pragma unroll
    for (int fm = 0; fm < 4; ++fm) acc[fm] = (f32x4){bb.x, bb.y, bb.z, bb.w};

#pragma unroll
    for (int c = 0; c < NCHUNK; ++c) {
      const int tap = c >> 2, ks = c & 3;
#pragma unroll
      for (int fm = 0; fm < 4; ++fm) {
        // x fragment (B operand): col = l15 -> t' within 16-row group fm.
        bf16x8 av = *(const bf16x8*)&xbuf[abase + (2 * tap + fm * 16) * XPITCH + ks * 32];
        acc[fm] = __builtin_amdgcn_mfma_f32_16x16x32_bf16(wreg[c], av, acc[fm], 0, 0, 0);
      }
    }

    // Epilogue: D row = o' = quad*4 + r (consecutive co), col = t' = l15.
    // Lane stores float4 at y[b, t0 + fm*16 + l15, f, co0 + quad*4].
    float* yb = y + (((size_t)b * T_ + t0 + l15) * F_ + f) * CO_ + co0 + quad * 4;
#pragma unroll
    for (int fm = 0; fm < 4; ++fm) {
      *(float4*)(yb + (size_t)(fm * 16) * (F_ * CO_)) =
          make_float4(acc[fm][0], acc[fm][1], acc[fm][2], acc[fm][3]);
    }

    if (j < NT - 1) {
      store_x(xs[(j + 1) & 1]);             // write NEXT tile into idle buffer
      if (j < NT - 2) load_x(t0 + 2 * TM);  // refill prefetch regs
      __syncthreads();                      // xs[(j+1)&1] ready for everyone
    }
  }
}

extern "C" void kernel_launch(void* const* d_in, const int* in_sizes, int n_in,
                              void* d_out, int out_size, void* d_ws, size_t ws_size,
                              hipStream_t stream) {
  const float* x = (const float*)d_in[0];
  const float* w = (const float*)d_in[1];
  const float* bias = (const float*)d_in[2];
  float* y = (float*)d_out;

  const size_t wt2_bytes = (size_t)F_ * NCHUNK * CHUNK_ELEMS * sizeof(uint16_t); // 3.0 MiB
  const int main_blocks = F_ * B_ * 2; // 1024 blocks -> 4 resident/CU (LDS-limited)

  if (ws_size >= wt2_bytes) {
    uint16_t* wt2 = (uint16_t*)d_ws;
    const int total = F_ * CO_ * CI_; // 524288
    repack_w<<<total / 256, 256, 0, stream>>>(w, wt2);
    conv_main<true><<<main_blocks, 512, 0, stream>>>(x, wt2, w, bias, y);
  } else {
    conv_main<false><<<main_blocks, 512, 0, stream>>>(x, (const uint16_t*)nullptr, w, bias, y);
  }
}

// Round 4
// 278.624 us; speedup vs baseline: 1.5930x; 1.0548x over previous
//
#include <hip/hip_runtime.h>
#include <stdint.h>

// Problem constants
#define B_ 16
#define T_ 512
#define F_ 32
#define CI_ 128
#define CO_ 128
#define K_ 3
#define LPAD 4              // DIL*(K-1)
#define TM 64               // output rows per tile
#define NT 8                // tiles per block (full T=512; R3's t-split regressed)
#define XROWS (TM + LPAD)   // 68 staged x rows
#define XPITCH 128          // bf16/row, NO pad: swizzle handles banks (row = 256B = 0 mod 32 banks)
#define WPITCH 32
#define CHUNK_ELEMS (CO_ * WPITCH) // 4096 elems per (tap,kstep) chunk
#define NCHUNK 12           // 3 taps * 4 ksteps of K=32
#define NXV 5               // ceil(68*32 / 512) float4 per thread

typedef __attribute__((ext_vector_type(8))) __bf16 bf16x8;
typedef __attribute__((ext_vector_type(4))) float f32x4;

__device__ __forceinline__ uint16_t f2bf(float x) {
  uint32_t u = __builtin_bit_cast(uint32_t, x);
  u += 0x7fffu + ((u >> 16) & 1u);
  return (uint16_t)(u >> 16);
}

// Coalesced repack: w[f][o][i][k] fp32 -> wt2[f][tap*4+kstep][o][32] bf16.
__global__ __launch_bounds__(256) void repack_w(const float* __restrict__ w,
                                                uint16_t* __restrict__ wt2) {
  int idx = blockIdx.x * 256 + threadIdx.x; // (f*CO+o)*CI + i
  int i = idx & (CI_ - 1);
  int fo = idx >> 7;
  int o = fo & (CO_ - 1);
  int f = fo >> 7;
  const float* src = w + (size_t)idx * K_;
  float a0 = src[0], a1 = src[1], a2 = src[2];
  size_t base = ((size_t)f * NCHUNK + (i >> 5)) * CHUNK_ELEMS + o * WPITCH + (i & 31);
  wt2[base] = f2bf(a0);
  wt2[base + 4 * (size_t)CHUNK_ELEMS] = f2bf(a1);
  wt2[base + 8 * (size_t)CHUNK_ELEMS] = f2bf(a2);
}

// Block = (f, b), 512 blocks = 2 resident/CU (R1 structure — best measured).
// 8 waves; wave owns 16 co with W pinned in 48 VGPRs (MFMA A operand).
// D = W(A) * x(B): D row = o, D col = t. This round:
//  - xs XOR-swizzled (granule ^= row&7), XPITCH=128: kills the 4-cyc/read
//    4-way bank conflict of the 136-pitch layout.
//  - Deferred y epilogue: tile j's stores are issued at the TOP of iter j+1,
//    so the pre-barrier vmcnt(0) drain no longer exposes store latency.
//  - load_x issued right after store_x at iter top: prefetch loads get a
//    full compute phase before the barrier drain.
template <bool PACKED>
__global__ __launch_bounds__(512, 4) void conv_main(
    const float* __restrict__ x, const uint16_t* __restrict__ wt2,
    const float* __restrict__ wraw, const float* __restrict__ bias,
    float* __restrict__ y) {
  __shared__ __align__(16) uint16_t xs[2][XROWS * XPITCH]; // 34,816 B

  const int bid = blockIdx.x;
  const int f = bid >> 4;   // 0..31
  const int b = bid & 15;   // 0..15

  const int tid = threadIdx.x;
  const int lane = tid & 63;
  const int wave = tid >> 6;   // 0..7 -> col group
  const int l15 = lane & 15;
  const int quad = lane >> 4;
  const int co0 = wave * 16;

  // ---- W fragments -> registers (once per block) ----
  // A-operand layout: lane row = l15 (o = co0+l15), k-chunk = quad*8..quad*8+7.
  bf16x8 wreg[NCHUNK];
  if constexpr (PACKED) {
    const uint16_t* wp = wt2 + (size_t)f * NCHUNK * CHUNK_ELEMS + (co0 + l15) * WPITCH + quad * 8;
#pragma unroll
    for (int c = 0; c < NCHUNK; ++c)
      wreg[c] = *(const bf16x8*)(wp + c * CHUNK_ELEMS);
  } else {
#pragma unroll
    for (int c = 0; c < NCHUNK; ++c) {
      int tap = c >> 2, i0 = (c & 3) * 32 + quad * 8;
      const float* ws = wraw + (((size_t)(f * CO_ + co0 + l15)) * CI_ + i0) * K_ + tap;
      union { bf16x8 v; uint16_t h[8]; } u;
#pragma unroll
      for (int j = 0; j < 8; ++j) u.h[j] = f2bf(ws[j * K_]);
      wreg[c] = u.v;
    }
  }
  // Bias along o: lane covers o = co0 + quad*4 + r, r=0..3.
  const float4 bb = *(const float4*)(bias + f * CO_ + co0 + quad * 4);

  const float* xb = x + ((size_t)b * T_ * F_ + f) * CI_;
  float4 xr[NXV];

  auto load_x = [&](int t0) { // issue global loads for tile window into regs
#pragma unroll
    for (int it = 0; it < NXV; ++it) {
      int idx = tid + it * 512;
      if (idx < XROWS * 32) {
        int row = idx >> 5, c4 = idx & 31;
        int t = t0 - LPAD + row;
        xr[it] = (t >= 0) ? *(const float4*)(xb + (size_t)t * (F_ * CI_) + c4 * 4)
                          : make_float4(0.f, 0.f, 0.f, 0.f);
      }
    }
  };
  // cvt + write staged regs into LDS buffer, XOR-swizzled:
  // logical [row][c4*4..c4*4+3] -> elem row*128 + ((g ^ (row&7))<<3) + (c4&1)*4,
  // g = c4>>1 (16B granule). Bijective per row; read side applies same XOR.
  auto store_x = [&](uint16_t* dst) {
#pragma unroll
    for (int it = 0; it < NXV; ++it) {
      int idx = tid + it * 512;
      if (idx < XROWS * 32) {
        int row = idx >> 5, c4 = idx & 31;
        uint2 pk;
        pk.x = (uint32_t)f2bf(xr[it].x) | ((uint32_t)f2bf(xr[it].y) << 16);
        pk.y = (uint32_t)f2bf(xr[it].z) | ((uint32_t)f2bf(xr[it].w) << 16);
        int e = row * XPITCH + ((((c4 >> 1) ^ (row & 7)) << 3) | ((c4 & 1) << 2));
        *(uint2*)&dst[e] = pk;
      }
    }
  };

  load_x(0);
  store_x(xs[0]);
  load_x(TM); // xr now holds tile 1
  __syncthreads();

  f32x4 accp[4]; // deferred-store accumulator (tile j-1)

#pragma unroll 1
  for (int j = 0; j < NT; ++j) {
    const int t0 = j * TM;
    const uint16_t* xbuf = xs[j & 1];

    // (1) Stage tile j+1 from regs into the idle buffer; refill xr with j+2.
    if (j < NT - 1) {
      store_x(xs[(j + 1) & 1]);
      if (j < NT - 2) load_x(t0 + 2 * TM);
    }

    // (2) Deferred y-store of tile j-1 (issued a full compute phase before
    //     the next barrier's vmcnt drain).
    if (j > 0) {
      const int tp = t0 - TM;
      float* yb = y + (((size_t)b * T_ + tp + l15) * F_ + f) * CO_ + co0 + quad * 4;
#pragma unroll
      for (int fm = 0; fm < 4; ++fm)
        *(float4*)(yb + (size_t)(fm * 16) * (F_ * CO_)) =
            make_float4(accp[fm][0], accp[fm][1], accp[fm][2], accp[fm][3]);
    }

    // (3) Compute tile j.
    f32x4 acc[4];
#pragma unroll
    for (int fm = 0; fm < 4; ++fm) acc[fm] = (f32x4){bb.x, bb.y, bb.z, bb.w};

#pragma unroll
    for (int c = 0; c < NCHUNK; ++c) {
      const int tap = c >> 2, ks = c & 3;
#pragma unroll
      for (int fm = 0; fm < 4; ++fm) {
        // x fragment (B operand): col = l15 -> t'; row = l15 + 2*tap + fm*16.
        const int row = l15 + 2 * tap;                 // fm*16 doesn't affect row&7
        const int e = (row + fm * 16) * XPITCH + (((ks * 4 + quad) ^ (row & 7)) << 3);
        bf16x8 av = *(const bf16x8*)&xbuf[e];
        acc[fm] = __builtin_amdgcn_mfma_f32_16x16x32_bf16(wreg[c], av, acc[fm], 0, 0, 0);
      }
    }
#pragma unroll
    for (int fm = 0; fm < 4; ++fm) accp[fm] = acc[fm];

    if (j < NT - 1) __syncthreads(); // xs[(j+1)&1] written by all; reads of xs[j&1] done
  }

  // Final tile's deferred store.
  {
    const int tp = (NT - 1) * TM;
    float* yb = y + (((size_t)b * T_ + tp + l15) * F_ + f) * CO_ + co0 + quad * 4;
#pragma unroll
    for (int fm = 0; fm < 4; ++fm)
      *(float4*)(yb + (size_t)(fm * 16) * (F_ * CO_)) =
          make_float4(accp[fm][0], accp[fm][1], accp[fm][2], accp[fm][3]);
  }
}

extern "C" void kernel_launch(void* const* d_in, const int* in_sizes, int n_in,
                              void* d_out, int out_size, void* d_ws, size_t ws_size,
                              hipStream_t stream) {
  const float* x = (const float*)d_in[0];
  const float* w = (const float*)d_in[1];
  const float* bias = (const float*)d_in[2];
  float* y = (float*)d_out;

  const size_t wt2_bytes = (size_t)F_ * NCHUNK * CHUNK_ELEMS * sizeof(uint16_t); // 3.0 MiB
  const int main_blocks = F_ * B_; // 512 blocks = 2 resident/CU

  if (ws_size >= wt2_bytes) {
    uint16_t* wt2 = (uint16_t*)d_ws;
    const int total = F_ * CO_ * CI_; // 524288
    repack_w<<<total / 256, 256, 0, stream>>>(w, wt2);
    conv_main<true><<<main_blocks, 512, 0, stream>>>(x, wt2, w, bias, y);
  } else {
    conv_main<false><<<main_blocks, 512, 0, stream>>>(x, (const uint16_t*)nullptr, w, bias, y);
  }
}

// Round 5
// 271.377 us; speedup vs baseline: 1.6355x; 1.0267x over previous
//
#include <hip/hip_runtime.h>
#include <stdint.h>

// Problem constants
#define B_ 16
#define T_ 512
#define F_ 32
#define CI_ 128
#define CO_ 128
#define K_ 3
#define LPAD 4              // DIL*(K-1)
#define TM 64               // output rows per tile
#define XROWS (TM + LPAD)   // 68 staged x rows
#define XPITCH 136          // bf16/row: 128 data + 8 pad (272B). NOTE: the 4 cyc/b128
                            // "conflict" count is structural (R4 swizzle A/B: identical).
#define WPITCH 32
#define CHUNK_ELEMS (CO_ * WPITCH) // 4096 elems per (tap,kstep) chunk
#define NCHUNK 12           // 3 taps * 4 ksteps of K=32
#define NXV 5               // ceil(68*32 / 512) float4 per thread

typedef __attribute__((ext_vector_type(8))) __bf16 bf16x8;
typedef __attribute__((ext_vector_type(4))) float f32x4;

__device__ __forceinline__ uint16_t f2bf(float x) {
  uint32_t u = __builtin_bit_cast(uint32_t, x);
  u += 0x7fffu + ((u >> 16) & 1u);
  return (uint16_t)(u >> 16);
}

// Coalesced repack: w[f][o][i][k] fp32 -> wt2[f][tap*4+kstep][o][32] bf16.
__global__ __launch_bounds__(256) void repack_w(const float* __restrict__ w,
                                                uint16_t* __restrict__ wt2) {
  int idx = blockIdx.x * 256 + threadIdx.x; // (f*CO+o)*CI + i
  int i = idx & (CI_ - 1);
  int fo = idx >> 7;
  int o = fo & (CO_ - 1);
  int f = fo >> 7;
  const float* src = w + (size_t)idx * K_;
  float a0 = src[0], a1 = src[1], a2 = src[2];
  size_t base = ((size_t)f * NCHUNK + (i >> 5)) * CHUNK_ELEMS + o * WPITCH + (i & 31);
  wt2[base] = f2bf(a0);
  wt2[base + 4 * (size_t)CHUNK_ELEMS] = f2bf(a1);
  wt2[base + 8 * (size_t)CHUNK_ELEMS] = f2bf(a2);
}

// Block = (f, b), 512 blocks = 2 resident/CU (R1 structure, best measured 98.5us).
// 8 waves; wave owns 16 co with W pinned in 48 VGPRs (MFMA A operand).
// D = W(A) * x(B): D row = o, D col = t.
//
// THIS ROUND (T4, counted barrier): the per-tile __syncthreads() lowered to
// s_waitcnt vmcnt(0) lgkmcnt(0) + s_barrier, draining the just-issued prefetch
// loads (full HBM latency + 70KB/CU transfer exposed EVERY tile) and the
// y-stores. Cross-wave correctness at this barrier only needs LDS visibility
// (lgkmcnt: store_x writes + all xs reads complete). So: lgkmcnt(0) + raw
// s_barrier; prefetch loads & y-stores stay in flight ACROSS the barrier.
// Compiler still inserts its own vmcnt(N) before xr is consumed (one phase
// later) -- register deps are tracked independently of the barrier.
template <bool PACKED>
__global__ __launch_bounds__(512, 4) void conv_main(
    const float* __restrict__ x, const uint16_t* __restrict__ wt2,
    const float* __restrict__ wraw, const float* __restrict__ bias,
    float* __restrict__ y) {
  __shared__ __align__(16) uint16_t xs[2][XROWS * XPITCH]; // 36,992 B

  const int bid = blockIdx.x;
  const int f = bid >> 4;   // 0..31
  const int b = bid & 15;   // 0..15

  const int tid = threadIdx.x;
  const int lane = tid & 63;
  const int wave = tid >> 6;   // 0..7 -> col group
  const int l15 = lane & 15;
  const int quad = lane >> 4;
  const int co0 = wave * 16;

  // ---- W fragments -> registers (once per block) ----
  // A-operand layout: lane row = l15 (o = co0+l15), k-chunk = quad*8..quad*8+7.
  bf16x8 wreg[NCHUNK];
  if constexpr (PACKED) {
    const uint16_t* wp = wt2 + (size_t)f * NCHUNK * CHUNK_ELEMS + (co0 + l15) * WPITCH + quad * 8;
#pragma unroll
    for (int c = 0; c < NCHUNK; ++c)
      wreg[c] = *(const bf16x8*)(wp + c * CHUNK_ELEMS);
  } else {
#pragma unroll
    for (int c = 0; c < NCHUNK; ++c) {
      int tap = c >> 2, i0 = (c & 3) * 32 + quad * 8;
      const float* ws = wraw + (((size_t)(f * CO_ + co0 + l15)) * CI_ + i0) * K_ + tap;
      union { bf16x8 v; uint16_t h[8]; } u;
#pragma unroll
      for (int j = 0; j < 8; ++j) u.h[j] = f2bf(ws[j * K_]);
      wreg[c] = u.v;
    }
  }
  // Bias along o: lane covers o = co0 + quad*4 + r, r=0..3.
  const float4 bb = *(const float4*)(bias + f * CO_ + co0 + quad * 4);

  const float* xb = x + ((size_t)b * T_ * F_ + f) * CI_;
  float4 xr[NXV];

  auto load_x = [&](int t0) { // issue global loads for tile window into regs
#pragma unroll
    for (int it = 0; it < NXV; ++it) {
      int idx = tid + it * 512;
      if (idx < XROWS * 32) {
        int row = idx >> 5, c4 = idx & 31;
        int t = t0 - LPAD + row;
        xr[it] = (t >= 0) ? *(const float4*)(xb + (size_t)t * (F_ * CI_) + c4 * 4)
                          : make_float4(0.f, 0.f, 0.f, 0.f);
      }
    }
  };
  auto store_x = [&](uint16_t* dst) { // cvt + write staged regs into LDS buffer
#pragma unroll
    for (int it = 0; it < NXV; ++it) {
      int idx = tid + it * 512;
      if (idx < XROWS * 32) {
        int row = idx >> 5, c4 = idx & 31;
        uint2 pk;
        pk.x = (uint32_t)f2bf(xr[it].x) | ((uint32_t)f2bf(xr[it].y) << 16);
        pk.y = (uint32_t)f2bf(xr[it].z) | ((uint32_t)f2bf(xr[it].w) << 16);
        *(uint2*)&dst[row * XPITCH + c4 * 4] = pk;
      }
    }
  };

  load_x(0);
  store_x(xs[0]);
  load_x(TM); // prefetch tile 1
  __syncthreads(); // prologue: full drain once is fine

  const int abase = l15 * XPITCH + quad * 8; // elem offset; rest is static imms

#pragma unroll 1
  for (int j = 0; j < 8; ++j) {
    const int t0 = j * TM;
    const uint16_t* xbuf = xs[j & 1];

    f32x4 acc[4];
#pragma unroll
    for (int fm = 0; fm < 4; ++fm) acc[fm] = (f32x4){bb.x, bb.y, bb.z, bb.w};

#pragma unroll
    for (int c = 0; c < NCHUNK; ++c) {
      const int tap = c >> 2, ks = c & 3;
#pragma unroll
      for (int fm = 0; fm < 4; ++fm) {
        // x fragment (B operand): col = l15 -> t' within 16-row group fm.
        bf16x8 av = *(const bf16x8*)&xbuf[abase + (2 * tap + fm * 16) * XPITCH + ks * 32];
        acc[fm] = __builtin_amdgcn_mfma_f32_16x16x32_bf16(wreg[c], av, acc[fm], 0, 0, 0);
      }
    }

    // Epilogue: D row = o' = quad*4 + r (consecutive co), col = t' = l15.
    // Stores stay outstanding across the counted barrier (no drain).
    float* yb = y + (((size_t)b * T_ + t0 + l15) * F_ + f) * CO_ + co0 + quad * 4;
#pragma unroll
    for (int fm = 0; fm < 4; ++fm) {
      *(float4*)(yb + (size_t)(fm * 16) * (F_ * CO_)) =
          make_float4(acc[fm][0], acc[fm][1], acc[fm][2], acc[fm][3]);
    }

    if (j < 7) {
      store_x(xs[(j + 1) & 1]);        // write NEXT tile into idle buffer
      if (j < 6) load_x((j + 2) * TM); // refill prefetch regs (stay in flight)
      // Counted barrier: only LDS ops must be visible across waves here.
      asm volatile("s_waitcnt lgkmcnt(0)" ::: "memory");
      __builtin_amdgcn_s_barrier();
    }
  }
}

extern "C" void kernel_launch(void* const* d_in, const int* in_sizes, int n_in,
                              void* d_out, int out_size, void* d_ws, size_t ws_size,
                              hipStream_t stream) {
  const float* x = (const float*)d_in[0];
  const float* w = (const float*)d_in[1];
  const float* bias = (const float*)d_in[2];
  float* y = (float*)d_out;

  const size_t wt2_bytes = (size_t)F_ * NCHUNK * CHUNK_ELEMS * sizeof(uint16_t); // 3.0 MiB
  const int main_blocks = F_ * B_; // 512 blocks = 2 resident/CU

  if (ws_size >= wt2_bytes) {
    uint16_t* wt2 = (uint16_t*)d_ws;
    const int total = F_ * CO_ * CI_; // 524288
    repack_w<<<total / 256, 256, 0, stream>>>(w, wt2);
    conv_main<true><<<main_blocks, 512, 0, stream>>>(x, wt2, w, bias, y);
  } else {
    conv_main<false><<<main_blocks, 512, 0, stream>>>(x, (const uint16_t*)nullptr, w, bias, y);
  }
}

// Round 6
// 256.841 us; speedup vs baseline: 1.7281x; 1.0566x over previous
//
#include <hip/hip_runtime.h>
#include <stdint.h>

// Problem constants
#define B_ 16
#define T_ 512
#define F_ 32
#define CI_ 128
#define CO_ 128
#define K_ 3
#define LPAD 4              // DIL*(K-1)
#define TM 64               // output rows per tile
#define XROWS (TM + LPAD)   // 68 staged x rows
#define XPITCH 136          // bf16/row: 128 data + 8 pad. 4cyc/b128 bank count is structural (R4 A/B).
#define WPITCH 32
#define CHUNK_ELEMS (CO_ * WPITCH) // 4096 elems per (tap,kstep) chunk
#define NCHUNK 12           // 3 taps * 4 ksteps of K=32
#define NXV 5               // ceil(68*32 / 512) float4 per thread

typedef __attribute__((ext_vector_type(8))) __bf16 bf16x8;
typedef __attribute__((ext_vector_type(4))) float f32x4;

__device__ __forceinline__ uint16_t f2bf(float x) {
  uint32_t u = __builtin_bit_cast(uint32_t, x);
  u += 0x7fffu + ((u >> 16) & 1u);
  return (uint16_t)(u >> 16);
}

// Coalesced repack: w[f][o][i][k] fp32 -> wt2[f][tap*4+kstep][o][32] bf16.
__global__ __launch_bounds__(256) void repack_w(const float* __restrict__ w,
                                                uint16_t* __restrict__ wt2) {
  int idx = blockIdx.x * 256 + threadIdx.x; // (f*CO+o)*CI + i
  int i = idx & (CI_ - 1);
  int fo = idx >> 7;
  int o = fo & (CO_ - 1);
  int f = fo >> 7;
  const float* src = w + (size_t)idx * K_;
  float a0 = src[0], a1 = src[1], a2 = src[2];
  size_t base = ((size_t)f * NCHUNK + (i >> 5)) * CHUNK_ELEMS + o * WPITCH + (i & 31);
  wt2[base] = f2bf(a0);
  wt2[base + 4 * (size_t)CHUNK_ELEMS] = f2bf(a1);
  wt2[base + 8 * (size_t)CHUNK_ELEMS] = f2bf(a2);
}

// Block = (f, b), 512 blocks = 2 resident/CU. 8 waves; wave owns 16 co with W
// pinned in 48 VGPRs (MFMA A operand). D = W(A) * x(B): D row = o, D col = t.
// Counted barrier (R5): lgkmcnt(0)+s_barrier only; loads/stores live across.
//
// THIS ROUND: block STAGGER. Evidence: all pipes <35% busy yet phase takes
// 29.5k cyc; the 2 co-resident blocks start together and have identical phase
// durations -> the whole CU's 16 waves burst memory simultaneously then idle
// at latency together, every phase (realized HBM 2.15 TB/s, bursty). Delay
// odd blocks by ~half a phase so the two resident blocks run anti-phase:
// one computes while the other waits. Parity key covers both plausible
// co-residency mappings ({2k,2k+1} and {k,k+256}).
template <bool PACKED>
__global__ __launch_bounds__(512, 4) void conv_main(
    const float* __restrict__ x, const uint16_t* __restrict__ wt2,
    const float* __restrict__ wraw, const float* __restrict__ bias,
    float* __restrict__ y) {
  __shared__ __align__(16) uint16_t xs[2][XROWS * XPITCH]; // 36,992 B

  const int bid = blockIdx.x;

  // ---- Stagger: desync co-resident blocks by ~16k cycles (~half phase) ----
  if (((bid >> 8) ^ bid) & 1) {
    __builtin_amdgcn_s_sleep(127);
    __builtin_amdgcn_s_sleep(127);
  }

  const int f = bid >> 4;   // 0..31
  const int b = bid & 15;   // 0..15

  const int tid = threadIdx.x;
  const int lane = tid & 63;
  const int wave = tid >> 6;   // 0..7 -> col group
  const int l15 = lane & 15;
  const int quad = lane >> 4;
  const int co0 = wave * 16;

  // ---- W fragments -> registers (once per block) ----
  // A-operand layout: lane row = l15 (o = co0+l15), k-chunk = quad*8..quad*8+7.
  bf16x8 wreg[NCHUNK];
  if constexpr (PACKED) {
    const uint16_t* wp = wt2 + (size_t)f * NCHUNK * CHUNK_ELEMS + (co0 + l15) * WPITCH + quad * 8;
#pragma unroll
    for (int c = 0; c < NCHUNK; ++c)
      wreg[c] = *(const bf16x8*)(wp + c * CHUNK_ELEMS);
  } else {
#pragma unroll
    for (int c = 0; c < NCHUNK; ++c) {
      int tap = c >> 2, i0 = (c & 3) * 32 + quad * 8;
      const float* ws = wraw + (((size_t)(f * CO_ + co0 + l15)) * CI_ + i0) * K_ + tap;
      union { bf16x8 v; uint16_t h[8]; } u;
#pragma unroll
      for (int j = 0; j < 8; ++j) u.h[j] = f2bf(ws[j * K_]);
      wreg[c] = u.v;
    }
  }
  // Bias along o: lane covers o = co0 + quad*4 + r, r=0..3.
  const float4 bb = *(const float4*)(bias + f * CO_ + co0 + quad * 4);

  const float* xb = x + ((size_t)b * T_ * F_ + f) * CI_;
  float4 xr[NXV];

  auto load_x = [&](int t0) { // issue global loads for tile window into regs
#pragma unroll
    for (int it = 0; it < NXV; ++it) {
      int idx = tid + it * 512;
      if (idx < XROWS * 32) {
        int row = idx >> 5, c4 = idx & 31;
        int t = t0 - LPAD + row;
        xr[it] = (t >= 0) ? *(const float4*)(xb + (size_t)t * (F_ * CI_) + c4 * 4)
                          : make_float4(0.f, 0.f, 0.f, 0.f);
      }
    }
  };
  auto store_x = [&](uint16_t* dst) { // cvt + write staged regs into LDS buffer
#pragma unroll
    for (int it = 0; it < NXV; ++it) {
      int idx = tid + it * 512;
      if (idx < XROWS * 32) {
        int row = idx >> 5, c4 = idx & 31;
        uint2 pk;
        pk.x = (uint32_t)f2bf(xr[it].x) | ((uint32_t)f2bf(xr[it].y) << 16);
        pk.y = (uint32_t)f2bf(xr[it].z) | ((uint32_t)f2bf(xr[it].w) << 16);
        *(uint2*)&dst[row * XPITCH + c4 * 4] = pk;
      }
    }
  };

  load_x(0);
  store_x(xs[0]);
  load_x(TM); // prefetch tile 1
  __syncthreads(); // prologue: full drain once is fine

  const int abase = l15 * XPITCH + quad * 8; // elem offset; rest is static imms

#pragma unroll 1
  for (int j = 0; j < 8; ++j) {
    const int t0 = j * TM;
    const uint16_t* xbuf = xs[j & 1];

    f32x4 acc[4];
#pragma unroll
    for (int fm = 0; fm < 4; ++fm) acc[fm] = (f32x4){bb.x, bb.y, bb.z, bb.w};

#pragma unroll
    for (int c = 0; c < NCHUNK; ++c) {
      const int tap = c >> 2, ks = c & 3;
#pragma unroll
      for (int fm = 0; fm < 4; ++fm) {
        // x fragment (B operand): col = l15 -> t' within 16-row group fm.
        bf16x8 av = *(const bf16x8*)&xbuf[abase + (2 * tap + fm * 16) * XPITCH + ks * 32];
        acc[fm] = __builtin_amdgcn_mfma_f32_16x16x32_bf16(wreg[c], av, acc[fm], 0, 0, 0);
      }
    }

    // Epilogue: D row = o' = quad*4 + r (consecutive co), col = t' = l15.
    // Stores stay outstanding across the counted barrier (no drain).
    float* yb = y + (((size_t)b * T_ + t0 + l15) * F_ + f) * CO_ + co0 + quad * 4;
#pragma unroll
    for (int fm = 0; fm < 4; ++fm) {
      *(float4*)(yb + (size_t)(fm * 16) * (F_ * CO_)) =
          make_float4(acc[fm][0], acc[fm][1], acc[fm][2], acc[fm][3]);
    }

    if (j < 7) {
      store_x(xs[(j + 1) & 1]);        // write NEXT tile into idle buffer
      if (j < 6) load_x((j + 2) * TM); // refill prefetch regs (stay in flight)
      // Counted barrier: only LDS ops must be visible across waves here.
      asm volatile("s_waitcnt lgkmcnt(0)" ::: "memory");
      __builtin_amdgcn_s_barrier();
    }
  }
}

extern "C" void kernel_launch(void* const* d_in, const int* in_sizes, int n_in,
                              void* d_out, int out_size, void* d_ws, size_t ws_size,
                              hipStream_t stream) {
  const float* x = (const float*)d_in[0];
  const float* w = (const float*)d_in[1];
  const float* bias = (const float*)d_in[2];
  float* y = (float*)d_out;

  const size_t wt2_bytes = (size_t)F_ * NCHUNK * CHUNK_ELEMS * sizeof(uint16_t); // 3.0 MiB
  const int main_blocks = F_ * B_; // 512 blocks = 2 resident/CU

  if (ws_size >= wt2_bytes) {
    uint16_t* wt2 = (uint16_t*)d_ws;
    const int total = F_ * CO_ * CI_; // 524288
    repack_w<<<total / 256, 256, 0, stream>>>(w, wt2);
    conv_main<true><<<main_blocks, 512, 0, stream>>>(x, wt2, w, bias, y);
  } else {
    conv_main<false><<<main_blocks, 512, 0, stream>>>(x, (const uint16_t*)nullptr, w, bias, y);
  }
}